// Round 17
// baseline (71.424 us; speedup 1.0000x reference)
//
#include <hip/hip_runtime.h>
#include <stdint.h>

// out[b,c] = <x_b/||x_b||, a_c/||a_c||>, B=16384, C=2048, D=1024, fp32 in/out.
// R17: INT8 row-scaled GEMM at R13's 2-blocks/CU structure.
//   Pass 1 (R16): per-row amax + sumsq; q = round(127 x/amax) i8;
//     scale = amax/(127*max(||x||,1e-8)); out = i32dot * sx * sa.
//   Pass 2: 128x128 tile, 4 waves (2x2 of 64x64), BK=128 i8 (128 B rows --
//     byte-identical LDS geometry to the PROVEN bf16 BK=64 tile: row&7 XOR
//     swizzle, 0 conflicts), NKT=8, dbuf LDS = 64 KiB -> 2 blocks/CU
//     (__launch_bounds__(256,2); regs ~160/wave, 2 waves/SIMD x 2 blocks).
//     One block's prologue/epilogue/vmcnt stalls overlap the other block's
//     MFMA loop (R13-verified mechanism); 134 MB of C-writes hide under
//     compute across the 8 grid rounds.
//   Per K-tile: stage(t+1) 8 DMA -> 16 ds_read_b128 -> 32 mfma_i32_16x16x64_i8
//   -> vmcnt(0) -> barrier. Race rule: stage targets parity P^1 only;
//   vmcnt -> barrier -> read at the tile boundary. XCD-chunked grid (2048%8=0).

#define D_DIM 1024
#define N_DIM 2048
#define BMt 128
#define BNt 128
#define BKt 128     // i8 elements per K-tile (128 B rows)
#define NKT 8       // D_DIM / BKt

typedef int i32x4 __attribute__((ext_vector_type(4)));

// One block per row (X rows then A rows): 256 threads x float4 = 1024 floats.
__global__ __launch_bounds__(256) void quant_rows(
        const float* __restrict__ x, const float* __restrict__ a,
        signed char* __restrict__ xq, signed char* __restrict__ aq,
        float* __restrict__ sx, float* __restrict__ sa, int Bn) {
    const int blk = blockIdx.x;
    const float* in  = (blk < Bn) ? x : a;
    signed char* outq = (blk < Bn) ? xq : aq;
    float* outs      = (blk < Bn) ? sx : sa;
    const int row = (blk < Bn) ? blk : blk - Bn;
    const int t = threadIdx.x;
    const float4 v = ((const float4*)(in + (size_t)row * D_DIM))[t];
    float ss = v.x * v.x + v.y * v.y + v.z * v.z + v.w * v.w;
    float mx = fmaxf(fmaxf(fabsf(v.x), fabsf(v.y)), fmaxf(fabsf(v.z), fabsf(v.w)));
#pragma unroll
    for (int o = 1; o < 64; o <<= 1) {
        ss += __shfl_xor(ss, o);
        mx = fmaxf(mx, __shfl_xor(mx, o));
    }
    __shared__ float redS[4], redM[4];
    if ((t & 63) == 0) { redS[t >> 6] = ss; redM[t >> 6] = mx; }
    __syncthreads();
    const float tot  = redS[0] + redS[1] + redS[2] + redS[3];
    const float amax = fmaxf(fmaxf(redM[0], redM[1]), fmaxf(redM[2], redM[3]));
    const float inv  = (amax > 0.0f) ? (127.0f / amax) : 0.0f;
    int q0 = __float2int_rn(v.x * inv), q1 = __float2int_rn(v.y * inv);
    int q2 = __float2int_rn(v.z * inv), q3 = __float2int_rn(v.w * inv);
    q0 = min(127, max(-127, q0)); q1 = min(127, max(-127, q1));
    q2 = min(127, max(-127, q2)); q3 = min(127, max(-127, q3));
    char4 o; o.x = (char)q0; o.y = (char)q1; o.z = (char)q2; o.w = (char)q3;
    ((char4*)(outq + (size_t)row * D_DIM))[t] = o;
    if (t == 0) outs[row] = amax / (127.0f * fmaxf(sqrtf(tot), 1e-8f));
}

__device__ __forceinline__ void gload_lds16(const void* g, void* l) {
    __builtin_amdgcn_global_load_lds(
        (const __attribute__((address_space(1))) void*)g,
        (__attribute__((address_space(3))) void*)l,
        16, 0, 0);
}

#define BAR()     asm volatile("s_barrier" ::: "memory")
#define VMCNT0()  asm volatile("s_waitcnt vmcnt(0)" ::: "memory")

// LDS (64 KiB): parity p: A at p*32768, B at p*32768 + 16384 (bytes).
// Each region = [128 rows][128 i8], 8 x 16B slots/row, slot ^= row&7.
template<int P, bool STAGE>
__device__ __forceinline__ void ktile(
        int t,
        const signed char* __restrict__ sA,  // A + (rowA0+grow)*D + gswz
        const signed char* __restrict__ sB,
        char* lds0, int dstT,                // tid*16
        const char* const (&pA)[2][2], const char* const (&pB)[2][2],
        i32x4 (&acc)[4][4])
{
    // stage A(t+1), B(t+1) into parity P^1 (readers drained at t-1 barrier)
    if constexpr (STAGE) {
        const int k1 = (t + 1) * BKt;
#pragma unroll
        for (int j = 0; j < 4; ++j) {
            gload_lds16(sA + (size_t)(j * 32) * D_DIM + k1,
                        lds0 + (P ^ 1) * 32768 + j * 4096 + dstT);
            gload_lds16(sB + (size_t)(j * 32) * D_DIM + k1,
                        lds0 + (P ^ 1) * 32768 + 16384 + j * 4096 + dstT);
        }
    }

    // fragment reads (parity P): 8 A + 8 B ds_read_b128, conflict-free
    i32x4 af[4][2], bf[4][2];
#pragma unroll
    for (int m = 0; m < 4; ++m)
#pragma unroll
        for (int kk = 0; kk < 2; ++kk)
            af[m][kk] = *(const i32x4*)(pA[P][kk] + m * 2048);
#pragma unroll
    for (int n = 0; n < 4; ++n)
#pragma unroll
        for (int kk = 0; kk < 2; ++kk)
            bf[n][kk] = *(const i32x4*)(pB[P][kk] + n * 2048);

    // 32 MFMA i8 K=64 (2 K-slices of the 128-K tile)
    __builtin_amdgcn_s_setprio(1);
#pragma unroll
    for (int m = 0; m < 4; ++m)
#pragma unroll
        for (int n = 0; n < 4; ++n)
#pragma unroll
            for (int kk = 0; kk < 2; ++kk)
                acc[m][n] = __builtin_amdgcn_mfma_i32_16x16x64_i8(
                    af[m][kk], bf[n][kk], acc[m][n], 0, 0, 0);
    __builtin_amdgcn_s_setprio(0);

    if constexpr (STAGE) {
        VMCNT0();   // my stage(t+1) landed
        BAR();      // all waves' landed -> next tile may read (race rule)
    }
}

__global__ __launch_bounds__(256, 2) void gemm128(
        const signed char* __restrict__ A,
        const signed char* __restrict__ Bm,
        const float* __restrict__ sx,
        const float* __restrict__ sb,
        float* __restrict__ Cg)
{
    __shared__ char lds0[65536];  // 64 KiB

    // XCD-chunked swizzle: 2048 wgs, 256 per XCD (contiguous bm span)
    const int nwg = gridDim.x;          // 2048
    const int cpx = nwg >> 3;           // 256
    const int wg  = ((int)blockIdx.x & 7) * cpx + ((int)blockIdx.x >> 3);
    const int bm  = wg >> 4;            // 0..127
    const int bn  = wg & 15;            // 0..15
    const int rowA0 = bm * BMt;
    const int rowB0 = bn * BNt;

    const int tid  = threadIdx.x;
    const int lane = tid & 63;
    const int wid  = tid >> 6;          // 0..3
    const int wr   = wid >> 1;          // 0..1 -> 64-row half
    const int wc   = wid & 1;           // 0..1 -> 64-col half
    const int rl = lane & 15, ts = lane >> 4, r7 = rl & 7;

    // per-lane frag base ptrs (row&7 == rl&7; kk=1 slot = 4^(ts^r7))
    const int swz0 = ((ts ^ r7) << 4);
    const int swz1 = (((4 + ts) ^ r7) << 4);
    const int aRow = (wr * 64 + rl) * 128;
    const int bRow = (wc * 64 + rl) * 128;
    const char* pA[2][2];
    const char* pB[2][2];
#pragma unroll
    for (int p = 0; p < 2; ++p) {
        pA[p][0] = lds0 + p * 32768 + aRow + swz0;
        pA[p][1] = lds0 + p * 32768 + aRow + swz1;
        pB[p][0] = lds0 + p * 32768 + 16384 + bRow + swz0;
        pB[p][1] = lds0 + p * 32768 + 16384 + bRow + swz1;
    }

    // staging: thread -> row = j*32 + (tid>>3), 16B slot = tid&7;
    // linear dest byte = j*4096 + tid*16; source col pre-swizzled (rule #21).
    const int gswz = (((tid & 7) ^ ((tid >> 3) & 7)) << 4);  // bytes (16 i8)
    const int grow = (tid >> 3);
    const signed char* sA = A  + (size_t)(rowA0 + grow) * D_DIM + gswz;
    const signed char* sB = Bm + (size_t)(rowB0 + grow) * D_DIM + gswz;
    const int dstT = tid * 16;

    i32x4 acc[4][4] = {};

    // prologue: stage tile 0 into parity 0; vmcnt(0) -> barrier
#pragma unroll
    for (int j = 0; j < 4; ++j) {
        gload_lds16(sA + (size_t)(j * 32) * D_DIM, lds0 + j * 4096 + dstT);
        gload_lds16(sB + (size_t)(j * 32) * D_DIM, lds0 + 16384 + j * 4096 + dstT);
    }
    VMCNT0();
    BAR();

#pragma unroll 1
    for (int t = 0; t < NKT - 2; t += 2) {        // t = 0,2,4 -> tiles 0..5
        ktile<0, true>(t,     sA, sB, lds0, dstT, pA, pB, acc);
        ktile<1, true>(t + 1, sA, sB, lds0, dstT, pA, pB, acc);
    }
    ktile<0, true >(NKT - 2, sA, sB, lds0, dstT, pA, pB, acc);  // tile 6
    ktile<1, false>(NKT - 1, sA, sB, lds0, dstT, pA, pB, acc);  // tile 7

    // epilogue: C/D layout col=lane&15, row=(lane>>4)*4+j (dtype-independent);
    // out = float(acc) * sx[row] * sb[col]
    const int crow0 = rowA0 + wr * 64 + ts * 4;
    const int ccol0 = rowB0 + wc * 64 + rl;
    float sbv[4];
#pragma unroll
    for (int n = 0; n < 4; ++n) sbv[n] = sb[ccol0 + n * 16];
#pragma unroll
    for (int m = 0; m < 4; ++m)
#pragma unroll
        for (int j = 0; j < 4; ++j) {
            const int row = crow0 + m * 16 + j;
            const float sav = sx[row];
#pragma unroll
            for (int n = 0; n < 4; ++n)
                Cg[(size_t)row * N_DIM + ccol0 + n * 16]
                    = (float)acc[m][n][j] * sav * sbv[n];
        }
}

extern "C" void kernel_launch(void* const* d_in, const int* in_sizes, int n_in,
                              void* d_out, int out_size, void* d_ws, size_t ws_size,
                              hipStream_t stream) {
    const float* x = (const float*)d_in[0];   // [B, D]
    const float* a = (const float*)d_in[1];   // [C, D]
    float* out = (float*)d_out;               // [B, C]

    const int Bn = in_sizes[0] / D_DIM;  // 16384
    const int Cn = in_sizes[1] / D_DIM;  // 2048

    signed char* xq = (signed char*)d_ws;                      // [B][D] i8
    signed char* aq = xq + (size_t)Bn * D_DIM;                 // [C][D] i8
    float* sx = (float*)(aq + (size_t)Cn * D_DIM);             // [B] f32
    float* sa = sx + Bn;                                       // [C] f32

    quant_rows<<<Bn + Cn, 256, 0, stream>>>(x, a, xq, aq, sx, sa, Bn);

    const int grid = (Bn / BMt) * (Cn / BNt);  // 128 * 16 = 2048
    gemm128<<<grid, 256, 0, stream>>>(xq, aq, sx, sa, out);
}